// Round 5
// baseline (1050.065 us; speedup 1.0000x reference)
//
#include <hip/hip_runtime.h>

#define NN 50000
#define TT 10
#define EE 1000000

// Destination-sorted edge geometry
#define NPART 512      // partitions (one block each per frame)
#define PARTN 98       // nodes per partition (512*98 = 50176 >= NN)
#define CHUNK 8192     // edges per hist/scatter block
#define NCHUNK 123     // ceil(EE/CHUNK)
#define CHPAD 128      // padded chunk slots in hist rows

__device__ __forceinline__ float sigmoidf_(float v) { return 1.0f / (1.0f + __expf(-v)); }
__device__ __forceinline__ float reluf_(float v) { return v > 0.0f ? v : 0.0f; }

__device__ __forceinline__ float4 ld4_(const float* __restrict__ p) {
    return *reinterpret_cast<const float4*>(p);
}
__device__ __forceinline__ void fma_row8(float* acc, const float* __restrict__ w, float f) {
    float4 a = ld4_(w), b = ld4_(w + 4);
    acc[0] += f * a.x; acc[1] += f * a.y; acc[2] += f * a.z; acc[3] += f * a.w;
    acc[4] += f * b.x; acc[5] += f * b.y; acc[6] += f * b.z; acc[7] += f * b.w;
}

// Serial MLP1 (pre_kernel only).
__device__ __forceinline__ float mlp1_eval_g(const float* feat,
                                             const float* __restrict__ w1,
                                             const float* __restrict__ b1,
                                             const float* __restrict__ w2,
                                             const float* __restrict__ b2,
                                             const float* __restrict__ w3,
                                             const float* __restrict__ b3) {
    float h1[32];
#pragma unroll
    for (int j = 0; j < 32; ++j) h1[j] = b1[j];
#pragma unroll
    for (int i = 0; i < 9; ++i) {
        float f = feat[i];
#pragma unroll
        for (int j = 0; j < 32; ++j) h1[j] += f * w1[i * 32 + j];
    }
#pragma unroll
    for (int j = 0; j < 32; ++j) h1[j] = reluf_(h1[j]);
    float h2[32];
#pragma unroll
    for (int j = 0; j < 32; ++j) h2[j] = b2[j];
#pragma unroll
    for (int i = 0; i < 32; ++i) {
        float f = h1[i];
#pragma unroll
        for (int j = 0; j < 32; ++j) h2[j] += f * w2[i * 32 + j];
    }
    float acc = b3[0];
#pragma unroll
    for (int j = 0; j < 32; ++j) acc += reluf_(h2[j]) * w3[j];
    return sigmoidf_(acc);
}

// Pre-pass: x transposes (sorted path) + init hidden / msg_base(frame 0) / agg.
__global__ void pre_kernel(const float* __restrict__ x,
                           const float* __restrict__ w1, const float* __restrict__ b1,
                           const float* __restrict__ w2, const float* __restrict__ b2,
                           const float* __restrict__ w3, const float* __restrict__ b3,
                           float* __restrict__ hidden, float* __restrict__ msg_base,
                           float* __restrict__ agg,
                           float* __restrict__ x0T, float* __restrict__ x1T,
                           int sorted) {
    int g = blockIdx.x * blockDim.x + threadIdx.x;
    if (g >= NN) return;
    float x00;
    if (sorted) {
        const float2* xr = reinterpret_cast<const float2*>(x + (size_t)g * TT * 2);
        float x0v[TT], x1v[TT];
#pragma unroll
        for (int tt = 0; tt < TT; ++tt) { float2 p = xr[tt]; x0v[tt] = p.x; x1v[tt] = p.y; }
#pragma unroll
        for (int tt = 0; tt < TT; ++tt) { x0T[tt * NN + g] = x0v[tt]; x1T[tt * NN + g] = x1v[tt]; }
        x00 = x0v[0];
    } else {
        x00 = x[(size_t)g * TT * 2];
    }
    agg[g] = 0.0f;
    float feat[9];
    feat[0] = x00;
#pragma unroll
    for (int k = 0; k < 8; ++k) feat[1 + k] = 0.0f;
    msg_base[g] = mlp1_eval_g(feat, w1, b1, w2, b2, w3, b3);
#pragma unroll
    for (int k = 0; k < 8; ++k) hidden[g * 8 + k] = 0.0f;
}

// --- One-time counting sort of edges by destination partition, per frame ---

// Per-(chunk, frame) LDS histogram of dst partitions.
__global__ __launch_bounds__(256) void hist_kernel(const int* __restrict__ ei,
                                                   unsigned* __restrict__ hist) {
    __shared__ unsigned cnt[NPART];
    const int c = blockIdx.x, t = blockIdx.y, tid = threadIdx.x;
    for (int i = tid; i < NPART; i += 256) cnt[i] = 0;
    __syncthreads();
    const int* dstp = ei + (size_t)(TT + t) * EE;
#pragma unroll
    for (int k = 0; k < CHUNK / 256; ++k) {
        int e = c * CHUNK + k * 256 + tid;
        if (e < EE) atomicAdd(&cnt[(unsigned)dstp[e] / PARTN], 1u);
    }
    __syncthreads();
    for (int p = tid; p < NPART; p += 256)
        hist[((size_t)(t * NPART + p)) * CHPAD + c] = cnt[p];
}

// Exclusive scan over chunks within each (t, part) row; total per row.
__global__ __launch_bounds__(64) void chunk_scan_kernel(unsigned* __restrict__ hist,
                                                        unsigned* __restrict__ total) {
    const int s = blockIdx.x;      // t*NPART + p
    const int lane = threadIdx.x;  // 0..63, two chunks per lane
    unsigned* row = hist + (size_t)s * CHPAD;
    const int c0 = lane * 2, c1 = lane * 2 + 1;
    unsigned a = (c0 < NCHUNK) ? row[c0] : 0u;
    unsigned b = (c1 < NCHUNK) ? row[c1] : 0u;
    unsigned s2 = a + b;
    unsigned xv = s2;
#pragma unroll
    for (int off = 1; off < 64; off <<= 1) {
        unsigned y = (unsigned)__shfl_up((int)xv, off);
        if (lane >= off) xv += y;
    }
    unsigned excl = xv - s2;
    if (c0 < NCHUNK) row[c0] = excl;
    if (c1 < NCHUNK) row[c1] = excl + a;
    if (lane == 63) total[s] = xv;
}

// Per-frame exclusive scan over partitions -> run bases (positions in [0, EE)).
__global__ void seg_scan_kernel(const unsigned* __restrict__ total,
                                unsigned* __restrict__ segBase) {
    int t = threadIdx.x;
    if (t < TT) {
        unsigned run = 0;
        for (int p = 0; p < NPART; ++p) {
            segBase[t * NPART + p] = run;
            run += total[t * NPART + p];
        }
    }
}

// Scatter edges into destination-sorted order: (src, local dst, ea value).
__global__ __launch_bounds__(256) void scatter_kernel(const int* __restrict__ ei,
                                                      const float* __restrict__ ea,
                                                      const unsigned* __restrict__ hist,
                                                      const unsigned* __restrict__ segBase,
                                                      int* __restrict__ srcS,
                                                      unsigned short* __restrict__ dstL,
                                                      float* __restrict__ eaS) {
    __shared__ unsigned lcur[NPART];
    const int c = blockIdx.x, t = blockIdx.y, tid = threadIdx.x;
    for (int p = tid; p < NPART; p += 256)
        lcur[p] = segBase[t * NPART + p] + hist[((size_t)(t * NPART + p)) * CHPAD + c];
    __syncthreads();
    const int* srcp = ei + (size_t)t * EE;
    const int* dstp = ei + (size_t)(TT + t) * EE;
    int* srcSt = srcS + (size_t)t * EE;
    unsigned short* dstLt = dstL + (size_t)t * EE;
    float* eaSt = eaS + (size_t)t * EE;
#pragma unroll
    for (int k = 0; k < CHUNK / 256; ++k) {
        int e = c * CHUNK + k * 256 + tid;
        if (e < EE) {
            int d = dstp[e];
            unsigned p = (unsigned)d / PARTN;
            unsigned pos = atomicAdd(&lcur[p], 1u);
            srcSt[pos] = srcp[e];
            dstLt[pos] = (unsigned short)(d - (int)(p * PARTN));
            eaSt[pos] = ea[(size_t)e * TT + t];
        }
    }
}

// Per-frame edge aggregation over sorted runs: one block per partition,
// LDS accumulate 98 floats, direct store to agg. No copies, no reduce.
__global__ __launch_bounds__(256) void edge_sorted_kernel(const int* __restrict__ srcS,
                                                          const unsigned short* __restrict__ dstL,
                                                          const float* __restrict__ eaS,
                                                          const unsigned* __restrict__ segBase,
                                                          const unsigned* __restrict__ total,
                                                          const float* __restrict__ msg_base,
                                                          float* __restrict__ agg, int t) {
    __shared__ float acc[PARTN];
    const int p = blockIdx.x, tid = threadIdx.x;
    const int base = p * PARTN;
    if (base >= NN) return;
    if (tid < PARTN) acc[tid] = 0.0f;
    __syncthreads();
    const unsigned s0 = segBase[t * NPART + p];
    const unsigned n = total[t * NPART + p];
    const int* srcSt = srcS + (size_t)t * EE;
    const unsigned short* dstLt = dstL + (size_t)t * EE;
    const float* eaSt = eaS + (size_t)t * EE;
    for (unsigned i = tid; i < n; i += 256) {
        float m = msg_base[srcSt[s0 + i]] * eaSt[s0 + i];
        atomicAdd(&acc[dstLt[s0 + i]], m);
    }
    __syncthreads();
    if (tid < PARTN && base + tid < NN) agg[base + tid] = acc[tid];
}

// Legacy fallback: device-atomic scatter.
__global__ void edge_kernel(const int* __restrict__ ei, const float* __restrict__ ea,
                            const float* __restrict__ msg_base, float* __restrict__ agg,
                            int t) {
    int g = blockIdx.x * blockDim.x + threadIdx.x;
    int e0 = g * 2;
    if (e0 >= EE) return;
    const int2 s = *reinterpret_cast<const int2*>(ei + (size_t)t * EE + e0);
    const int2 d = *reinterpret_cast<const int2*>(ei + (size_t)(TT + t) * EE + e0);
    atomicAdd(&agg[d.x], msg_base[s.x] * ea[(size_t)e0 * TT + t]);
    atomicAdd(&agg[d.y], msg_base[s.y] * ea[(size_t)(e0 + 1) * TT + t]);
}

// 4-lane-per-node node update (unchanged math from round 4, minus aggB reduce).
template <int SORTED>
__global__ __launch_bounds__(256) void node4_kernel(
        const float* __restrict__ x,
        const float* __restrict__ x0T, const float* __restrict__ x1T,
        const float* __restrict__ m1w1, const float* __restrict__ m1b1,
        const float* __restrict__ m1w2, const float* __restrict__ m1b2,
        const float* __restrict__ m1w3, const float* __restrict__ m1b3,
        const float* __restrict__ m2w1, const float* __restrict__ m2b1,
        const float* __restrict__ m2w2, const float* __restrict__ m2b2,
        const float* __restrict__ ow1, const float* __restrict__ ob1,
        const float* __restrict__ ow2, const float* __restrict__ ob2,
        float* __restrict__ hidden, float* __restrict__ msg_base,
        float* __restrict__ agg, float* __restrict__ out, int t) {
    const int gid = blockIdx.x * 256 + threadIdx.x;
    const int n = gid >> 2;
    const int q = gid & 3;
    if (n >= NN) return;

    const float a = agg[n];
    const float x1 = SORTED ? x1T[t * NN + n] : x[(size_t)n * TT * 2 + t * 2 + 1];

    // hidden: own float2, exchange for permuted full set
    float2 hme = *reinterpret_cast<const float2*>(hidden + (size_t)n * 8 + q * 2);
    float hid[8];
    hid[0] = hme.x; hid[1] = hme.y;
    hid[2] = __shfl_xor(hid[0], 1); hid[3] = __shfl_xor(hid[1], 1);
    hid[4] = __shfl_xor(hid[0], 2); hid[5] = __shfl_xor(hid[1], 2);
    hid[6] = __shfl_xor(hid[2], 2); hid[7] = __shfl_xor(hid[3], 2);

    // MLP2 layer1: columns [q*8, q*8+8)
    float acc[8];
    {
        float4 bA = ld4_(m2b1 + q * 8), bB = ld4_(m2b1 + q * 8 + 4);
        acc[0] = bA.x; acc[1] = bA.y; acc[2] = bA.z; acc[3] = bA.w;
        acc[4] = bB.x; acc[5] = bB.y; acc[6] = bB.z; acc[7] = bB.w;
    }
    fma_row8(acc, m2w1 + q * 8, x1);
#pragma unroll
    for (int g = 0; g < 4; ++g) {
        int rq = (q ^ g) * 2;
        fma_row8(acc, m2w1 + (size_t)(1 + rq) * 32 + q * 8, hid[g * 2 + 0]);
        fma_row8(acc, m2w1 + (size_t)(2 + rq) * 32 + q * 8, hid[g * 2 + 1]);
    }
    fma_row8(acc, m2w1 + (size_t)9 * 32 + q * 8, a);
    float u1[8];
#pragma unroll
    for (int jj = 0; jj < 8; ++jj) u1[jj] = reluf_(acc[jj]);

    // MLP2 layer2: quad-partial, reduce -> all lanes hold hn[0..7]
    float pk[8];
#pragma unroll
    for (int k = 0; k < 8; ++k) pk[k] = 0.0f;
#pragma unroll
    for (int jj = 0; jj < 8; ++jj)
        fma_row8(pk, m2w2 + (size_t)(q * 8 + jj) * 8, u1[jj]);
#pragma unroll
    for (int k = 0; k < 8; ++k) {
        pk[k] += __shfl_xor(pk[k], 1);
        pk[k] += __shfl_xor(pk[k], 2);
    }
    float hn[8];
    {
        float4 b2A = ld4_(m2b2), b2B = ld4_(m2b2 + 4);
        hn[0] = tanhf(reluf_(pk[0] + b2A.x));
        hn[1] = tanhf(reluf_(pk[1] + b2A.y));
        hn[2] = tanhf(reluf_(pk[2] + b2A.z));
        hn[3] = tanhf(reluf_(pk[3] + b2A.w));
        hn[4] = tanhf(reluf_(pk[4] + b2B.x));
        hn[5] = tanhf(reluf_(pk[5] + b2B.y));
        hn[6] = tanhf(reluf_(pk[6] + b2B.z));
        hn[7] = tanhf(reluf_(pk[7] + b2B.w));
    }
    if (q == 0) {
        *reinterpret_cast<float4*>(hidden + (size_t)n * 8)     = make_float4(hn[0], hn[1], hn[2], hn[3]);
        *reinterpret_cast<float4*>(hidden + (size_t)n * 8 + 4) = make_float4(hn[4], hn[5], hn[6], hn[7]);
    }

    // h2o
    float o1v[4];
    {
        float4 ob = ld4_(ob1 + q * 4);
        o1v[0] = ob.x; o1v[1] = ob.y; o1v[2] = ob.z; o1v[3] = ob.w;
    }
#pragma unroll
    for (int k = 0; k < 8; ++k) {
        float4 w = ld4_(ow1 + k * 16 + q * 4);
        o1v[0] += hn[k] * w.x; o1v[1] += hn[k] * w.y;
        o1v[2] += hn[k] * w.z; o1v[3] += hn[k] * w.w;
    }
    {
        float4 w2v = ld4_(ow2 + q * 4);
        float oop = reluf_(o1v[0]) * w2v.x + reluf_(o1v[1]) * w2v.y +
                    reluf_(o1v[2]) * w2v.z + reluf_(o1v[3]) * w2v.w;
        oop += __shfl_xor(oop, 1);
        oop += __shfl_xor(oop, 2);
        if (q == 0) out[t * NN + n] = sigmoidf_(oop + ob2[0]);
    }

    // MLP1 for next frame's msg_base
    if (t < TT - 1) {
        float feat0 = SORTED ? x0T[(t + 1) * NN + n] : x[(size_t)n * TT * 2 + (t + 1) * 2];
        float h1[8];
        {
            float4 bA = ld4_(m1b1 + q * 8), bB = ld4_(m1b1 + q * 8 + 4);
            h1[0] = bA.x; h1[1] = bA.y; h1[2] = bA.z; h1[3] = bA.w;
            h1[4] = bB.x; h1[5] = bB.y; h1[6] = bB.z; h1[7] = bB.w;
        }
        fma_row8(h1, m1w1 + q * 8, feat0);
#pragma unroll
        for (int k = 0; k < 8; ++k)
            fma_row8(h1, m1w1 + (size_t)(1 + k) * 32 + q * 8, hn[k]);
#pragma unroll
        for (int jj = 0; jj < 8; ++jj) h1[jj] = reluf_(h1[jj]);

        float h1x[32];
#pragma unroll
        for (int jj = 0; jj < 8; ++jj) h1x[jj] = h1[jj];
#pragma unroll
        for (int jj = 0; jj < 8; ++jj) h1x[8 + jj]  = __shfl_xor(h1x[jj], 1);
#pragma unroll
        for (int jj = 0; jj < 8; ++jj) h1x[16 + jj] = __shfl_xor(h1x[jj], 2);
#pragma unroll
        for (int jj = 0; jj < 8; ++jj) h1x[24 + jj] = __shfl_xor(h1x[8 + jj], 2);

        float acc8[8];
        {
            float4 bA = ld4_(m1b2 + q * 8), bB = ld4_(m1b2 + q * 8 + 4);
            acc8[0] = bA.x; acc8[1] = bA.y; acc8[2] = bA.z; acc8[3] = bA.w;
            acc8[4] = bB.x; acc8[5] = bB.y; acc8[6] = bB.z; acc8[7] = bB.w;
        }
#pragma unroll
        for (int g = 0; g < 4; ++g) {
            int rb = (q ^ g) * 8;
#pragma unroll
            for (int jj = 0; jj < 8; ++jj)
                fma_row8(acc8, m1w2 + (size_t)(rb + jj) * 32 + q * 8, h1x[g * 8 + jj]);
        }
        float s3;
        {
            float4 w3a = ld4_(m1w3 + q * 8), w3b = ld4_(m1w3 + q * 8 + 4);
            s3 = reluf_(acc8[0]) * w3a.x + reluf_(acc8[1]) * w3a.y +
                 reluf_(acc8[2]) * w3a.z + reluf_(acc8[3]) * w3a.w +
                 reluf_(acc8[4]) * w3b.x + reluf_(acc8[5]) * w3b.y +
                 reluf_(acc8[6]) * w3b.z + reluf_(acc8[7]) * w3b.w;
        }
        s3 += __shfl_xor(s3, 1);
        s3 += __shfl_xor(s3, 2);
        if (q == 0) {
            msg_base[n] = sigmoidf_(s3 + m1b3[0]);
            if (!SORTED) agg[n] = 0.0f;
        }
    }
}

extern "C" void kernel_launch(void* const* d_in, const int* in_sizes, int n_in,
                              void* d_out, int out_size, void* d_ws, size_t ws_size,
                              hipStream_t stream) {
    (void)in_sizes; (void)n_in; (void)out_size;
    const float* x    = (const float*)d_in[0];
    const int*   ei   = (const int*)d_in[1];
    const float* ea   = (const float*)d_in[2];
    const float* m1w1 = (const float*)d_in[3];
    const float* m1b1 = (const float*)d_in[4];
    const float* m1w2 = (const float*)d_in[5];
    const float* m1b2 = (const float*)d_in[6];
    const float* m1w3 = (const float*)d_in[7];
    const float* m1b3 = (const float*)d_in[8];
    const float* m2w1 = (const float*)d_in[9];
    const float* m2b1 = (const float*)d_in[10];
    const float* m2w2 = (const float*)d_in[11];
    const float* m2b2 = (const float*)d_in[12];
    const float* ow1  = (const float*)d_in[13];
    const float* ob1  = (const float*)d_in[14];
    const float* ow2  = (const float*)d_in[15];
    const float* ob2  = (const float*)d_in[16];
    float* out = (float*)d_out;

    // Workspace carve (bytes)
    char* wp = (char*)d_ws;
    float* hidden   = (float*)wp; wp += (size_t)NN * 8 * 4;
    float* msg_base = (float*)wp; wp += (size_t)NN * 4;
    float* agg      = (float*)wp; wp += (size_t)NN * 4;
    float* x0T      = (float*)wp; wp += (size_t)NN * TT * 4;
    float* x1T      = (float*)wp; wp += (size_t)NN * TT * 4;
    float* eaS      = (float*)wp; wp += (size_t)TT * EE * 4;
    int*   srcS     = (int*)wp;   wp += (size_t)TT * EE * 4;
    unsigned short* dstL = (unsigned short*)wp; wp += (size_t)TT * EE * 2;
    unsigned* hist    = (unsigned*)wp; wp += (size_t)TT * NPART * CHPAD * 4;
    unsigned* total   = (unsigned*)wp; wp += (size_t)TT * NPART * 4;
    unsigned* segBase = (unsigned*)wp; wp += (size_t)TT * NPART * 4;
    size_t need = (size_t)(wp - (char*)d_ws);

    int sorted = (ws_size >= need) ? 1 : 0;

    dim3 blk(256);
    int nodeBlocks  = (NN + 255) / 256;
    int node4Blocks = (NN * 4 + 255) / 256;
    int edgeBlocksLegacy = (EE / 2 + 255) / 256;

    pre_kernel<<<nodeBlocks, blk, 0, stream>>>(x, m1w1, m1b1, m1w2, m1b2, m1w3, m1b3,
                                               hidden, msg_base, agg, x0T, x1T, sorted);
    if (sorted) {
        hist_kernel<<<dim3(NCHUNK, TT), blk, 0, stream>>>(ei, hist);
        chunk_scan_kernel<<<TT * NPART, dim3(64), 0, stream>>>(hist, total);
        seg_scan_kernel<<<1, dim3(64), 0, stream>>>(total, segBase);
        scatter_kernel<<<dim3(NCHUNK, TT), blk, 0, stream>>>(ei, ea, hist, segBase,
                                                             srcS, dstL, eaS);
    }
    for (int t = 0; t < TT; ++t) {
        if (sorted) {
            edge_sorted_kernel<<<NPART, blk, 0, stream>>>(srcS, dstL, eaS, segBase, total,
                                                          msg_base, agg, t);
            node4_kernel<1><<<node4Blocks, blk, 0, stream>>>(
                x, x0T, x1T,
                m1w1, m1b1, m1w2, m1b2, m1w3, m1b3,
                m2w1, m2b1, m2w2, m2b2,
                ow1, ob1, ow2, ob2,
                hidden, msg_base, agg, out, t);
        } else {
            edge_kernel<<<edgeBlocksLegacy, blk, 0, stream>>>(ei, ea, msg_base, agg, t);
            node4_kernel<0><<<node4Blocks, blk, 0, stream>>>(
                x, x0T, x1T,
                m1w1, m1b1, m1w2, m1b2, m1w3, m1b3,
                m2w1, m2b1, m2w2, m2b2,
                ow1, ob1, ow2, ob2,
                hidden, msg_base, agg, out, t);
        }
    }
}

// Round 6
// 675.174 us; speedup vs baseline: 1.5553x; 1.5553x over previous
//
#include <hip/hip_runtime.h>

#define NN 50000
#define TT 10
#define EE 1000000

#define NB 16          // dst buckets (node ranges)
#define BN 3125        // nodes per bucket (NB*BN == NN)
#define NSLICE 32      // slices per bucket in per-frame edge kernel
#define CHUNK 2048     // edges per sort chunk
#define NCHUNK 489     // ceil(EE/CHUNK)
#define CHPAD 512      // padded chunk slots per (t,b) hist row
#define KPT (CHUNK / 256)

__device__ __forceinline__ float sigmoidf_(float v) { return 1.0f / (1.0f + __expf(-v)); }
__device__ __forceinline__ float reluf_(float v) { return v > 0.0f ? v : 0.0f; }

__device__ __forceinline__ float4 ld4_(const float* __restrict__ p) {
    return *reinterpret_cast<const float4*>(p);
}
__device__ __forceinline__ void fma_row8(float* acc, const float* __restrict__ w, float f) {
    float4 a = ld4_(w), b = ld4_(w + 4);
    acc[0] += f * a.x; acc[1] += f * a.y; acc[2] += f * a.z; acc[3] += f * a.w;
    acc[4] += f * b.x; acc[5] += f * b.y; acc[6] += f * b.z; acc[7] += f * b.w;
}

// Serial MLP1 (pre_kernel only).
__device__ __forceinline__ float mlp1_eval_g(const float* feat,
                                             const float* __restrict__ w1,
                                             const float* __restrict__ b1,
                                             const float* __restrict__ w2,
                                             const float* __restrict__ b2,
                                             const float* __restrict__ w3,
                                             const float* __restrict__ b3) {
    float h1[32];
#pragma unroll
    for (int j = 0; j < 32; ++j) h1[j] = b1[j];
#pragma unroll
    for (int i = 0; i < 9; ++i) {
        float f = feat[i];
#pragma unroll
        for (int j = 0; j < 32; ++j) h1[j] += f * w1[i * 32 + j];
    }
#pragma unroll
    for (int j = 0; j < 32; ++j) h1[j] = reluf_(h1[j]);
    float h2[32];
#pragma unroll
    for (int j = 0; j < 32; ++j) h2[j] = b2[j];
#pragma unroll
    for (int i = 0; i < 32; ++i) {
        float f = h1[i];
#pragma unroll
        for (int j = 0; j < 32; ++j) h2[j] += f * w2[i * 32 + j];
    }
    float acc = b3[0];
#pragma unroll
    for (int j = 0; j < 32; ++j) acc += reluf_(h2[j]) * w3[j];
    return sigmoidf_(acc);
}

// Pre-pass: x transposes (sorted path) + init hidden / msg_base(frame 0) / agg.
__global__ void pre_kernel(const float* __restrict__ x,
                           const float* __restrict__ w1, const float* __restrict__ b1,
                           const float* __restrict__ w2, const float* __restrict__ b2,
                           const float* __restrict__ w3, const float* __restrict__ b3,
                           float* __restrict__ hidden, float* __restrict__ msg_base,
                           float* __restrict__ agg,
                           float* __restrict__ x0T, float* __restrict__ x1T,
                           int sorted) {
    int g = blockIdx.x * blockDim.x + threadIdx.x;
    if (g >= NN) return;
    float x00;
    if (sorted) {
        const float2* xr = reinterpret_cast<const float2*>(x + (size_t)g * TT * 2);
        float x0v[TT], x1v[TT];
#pragma unroll
        for (int tt = 0; tt < TT; ++tt) { float2 p = xr[tt]; x0v[tt] = p.x; x1v[tt] = p.y; }
#pragma unroll
        for (int tt = 0; tt < TT; ++tt) { x0T[tt * NN + g] = x0v[tt]; x1T[tt * NN + g] = x1v[tt]; }
        x00 = x0v[0];
    } else {
        x00 = x[(size_t)g * TT * 2];
    }
    agg[g] = 0.0f;
    float feat[9];
    feat[0] = x00;
#pragma unroll
    for (int k = 0; k < 8; ++k) feat[1 + k] = 0.0f;
    msg_base[g] = mlp1_eval_g(feat, w1, b1, w2, b2, w3, b3);
#pragma unroll
    for (int k = 0; k < 8; ++k) hidden[g * 8 + k] = 0.0f;
}

// --- One-time 16-bucket counting sort of edges by dst range, all frames ---

// K1: per-(chunk) block, loop frames: LDS hist (4 wave replicas) -> chist counts.
__global__ __launch_bounds__(256) void hist16_kernel(const int* __restrict__ ei,
                                                     unsigned* __restrict__ chist) {
    __shared__ unsigned h4[4][NB];
    const int c = blockIdx.x, tid = threadIdx.x, w = tid >> 6;
    for (int t = 0; t < TT; ++t) {
        for (int i = tid; i < 4 * NB; i += 256) (&h4[0][0])[i] = 0u;
        __syncthreads();
        const int* dstp = ei + (size_t)(TT + t) * EE;
#pragma unroll
        for (int k = 0; k < KPT; ++k) {
            int e = c * CHUNK + k * 256 + tid;
            if (e < EE) atomicAdd(&h4[w][(unsigned)dstp[e] / BN], 1u);
        }
        __syncthreads();
        if (tid < NB) {
            unsigned s = h4[0][tid] + h4[1][tid] + h4[2][tid] + h4[3][tid];
            chist[((size_t)(t * NB + tid)) * CHPAD + c] = s;
        }
        __syncthreads();
    }
}

// K2: in-place exclusive scan of each (t,b) row over chunks; row total out.
__global__ __launch_bounds__(64) void scan_kernel(unsigned* __restrict__ chist,
                                                  unsigned* __restrict__ total) {
    const int row = blockIdx.x;  // t*NB + b
    unsigned* r = chist + (size_t)row * CHPAD;
    const int lane = threadIdx.x;
    unsigned v[8];
    unsigned s = 0;
#pragma unroll
    for (int j = 0; j < 8; ++j) {
        int c = lane * 8 + j;
        unsigned xx = (c < NCHUNK) ? r[c] : 0u;
        v[j] = s; s += xx;
    }
    unsigned inc = s;
#pragma unroll
    for (int off = 1; off < 64; off <<= 1) {
        unsigned y = (unsigned)__shfl_up((int)inc, off);
        if (lane >= off) inc += y;
    }
    unsigned excl = inc - s;
#pragma unroll
    for (int j = 0; j < 8; ++j) {
        int c = lane * 8 + j;
        if (c < NCHUNK) r[c] = excl + v[j];
    }
    if (lane == 63) total[row] = inc;
}

// K2b: per-frame bucket bases.
__global__ void segbase_kernel(const unsigned* __restrict__ total,
                               unsigned* __restrict__ segBase) {
    int t = threadIdx.x;
    if (t < TT) {
        unsigned run = 0;
        for (int b = 0; b < NB; ++b) { segBase[t * NB + b] = run; run += total[t * NB + b]; }
    }
}

// K3: reorder. One block per chunk; ea row (all 10 frames) held in registers
// (read once, coalesced); per frame: local hist -> LDS-staged reorder ->
// coalesced run write-out of packed int4 records (src, dst, ea_bits, 0).
__global__ __launch_bounds__(256) void reorder_kernel(const int* __restrict__ ei,
                                                      const float* __restrict__ ea,
                                                      const unsigned* __restrict__ chist,
                                                      const unsigned* __restrict__ segBase,
                                                      int4* __restrict__ srt) {
    __shared__ int4 stg[CHUNK];
    __shared__ unsigned h4[4][NB];
    __shared__ unsigned lbase[NB], gbase[NB], cur[NB];
    __shared__ unsigned cnt_s;
    const int c = blockIdx.x, tid = threadIdx.x, w = tid >> 6;

    float ear[KPT][TT];
#pragma unroll
    for (int k = 0; k < KPT; ++k) {
        int e = c * CHUNK + k * 256 + tid;
        if (e < EE) {
            const float2* row = reinterpret_cast<const float2*>(ea + (size_t)e * TT);
#pragma unroll
            for (int j2 = 0; j2 < 5; ++j2) {
                float2 p = row[j2];
                ear[k][2 * j2] = p.x; ear[k][2 * j2 + 1] = p.y;
            }
        } else {
#pragma unroll
            for (int tt = 0; tt < TT; ++tt) ear[k][tt] = 0.0f;
        }
    }

#pragma unroll
    for (int t = 0; t < TT; ++t) {
        for (int i = tid; i < 4 * NB; i += 256) (&h4[0][0])[i] = 0u;
        __syncthreads();
        const int* srcp = ei + (size_t)t * EE;
        const int* dstp = ei + (size_t)(TT + t) * EE;
        int se[KPT], de[KPT];
#pragma unroll
        for (int k = 0; k < KPT; ++k) {
            int e = c * CHUNK + k * 256 + tid;
            if (e < EE) {
                se[k] = srcp[e];
                de[k] = dstp[e];
                atomicAdd(&h4[w][(unsigned)de[k] / BN], 1u);
            } else {
                de[k] = -1; se[k] = 0;
            }
        }
        __syncthreads();
        if (tid == 0) {
            unsigned run = 0;
            for (int b = 0; b < NB; ++b) {
                unsigned hb = h4[0][b] + h4[1][b] + h4[2][b] + h4[3][b];
                lbase[b] = run; cur[b] = run; run += hb;
            }
            cnt_s = run;
        }
        if (tid < NB)
            gbase[tid] = segBase[t * NB + tid] + chist[((size_t)(t * NB + tid)) * CHPAD + c];
        __syncthreads();
#pragma unroll
        for (int k = 0; k < KPT; ++k) {
            if (de[k] >= 0) {
                unsigned b = (unsigned)de[k] / BN;
                unsigned slot = atomicAdd(&cur[b], 1u);
                stg[slot] = make_int4(se[k], de[k], __float_as_int(ear[k][t]), 0);
            }
        }
        __syncthreads();
        const unsigned cnt = cnt_s;
        int4* dstT = srt + (size_t)t * EE;
        for (unsigned i = tid; i < cnt; i += 256) {
            int4 rec = stg[i];
            unsigned b = (unsigned)rec.y / BN;
            dstT[gbase[b] + (i - lbase[b])] = rec;
        }
        __syncthreads();
    }
}

// Per-frame edge aggregation: 512 blocks = 16 buckets x 32 slices.
// LDS image of the bucket's 3125 nodes; write one slice copy (12.5 KB).
__global__ __launch_bounds__(256) void edge_srt_kernel(const int4* __restrict__ srt,
                                                       const unsigned* __restrict__ segBase,
                                                       const unsigned* __restrict__ total,
                                                       const float* __restrict__ msg_base,
                                                       float* __restrict__ aggB, int t) {
    __shared__ float acc[BN];
    const int blk = blockIdx.x;
    const int b = blk >> 5, s = blk & 31;
    const int tid = threadIdx.x;
    for (int i = tid; i < BN; i += 256) acc[i] = 0.0f;
    __syncthreads();
    const unsigned base = segBase[t * NB + b];
    const unsigned cnt = total[t * NB + b];
    const unsigned i0 = (unsigned)(((unsigned long long)cnt * s) >> 5);
    const unsigned i1 = (unsigned)(((unsigned long long)cnt * (s + 1)) >> 5);
    const int4* p = srt + (size_t)t * EE + base;
    const int nbase = b * BN;
    for (unsigned i = i0 + tid; i < i1; i += 256) {
        int4 rec = p[i];
        float m = msg_base[rec.x] * __int_as_float(rec.z);
        atomicAdd(&acc[rec.y - nbase], m);
    }
    __syncthreads();
    float* o = aggB + (size_t)(b * NSLICE + s) * BN;
    for (int i = tid; i < BN; i += 256) o[i] = acc[i];
}

// Legacy fallback: device-atomic scatter.
__global__ void edge_kernel(const int* __restrict__ ei, const float* __restrict__ ea,
                            const float* __restrict__ msg_base, float* __restrict__ agg,
                            int t) {
    int g = blockIdx.x * blockDim.x + threadIdx.x;
    int e0 = g * 2;
    if (e0 >= EE) return;
    const int2 s = *reinterpret_cast<const int2*>(ei + (size_t)t * EE + e0);
    const int2 d = *reinterpret_cast<const int2*>(ei + (size_t)(TT + t) * EE + e0);
    atomicAdd(&agg[d.x], msg_base[s.x] * ea[(size_t)e0 * TT + t]);
    atomicAdd(&agg[d.y], msg_base[s.y] * ea[(size_t)(e0 + 1) * TT + t]);
}

// 4-lane-per-node node update; SORTED path reduces 32 slice copies (8/lane).
template <int SORTED>
__global__ __launch_bounds__(256) void node4_kernel(
        const float* __restrict__ x,
        const float* __restrict__ x0T, const float* __restrict__ x1T,
        const float* __restrict__ m1w1, const float* __restrict__ m1b1,
        const float* __restrict__ m1w2, const float* __restrict__ m1b2,
        const float* __restrict__ m1w3, const float* __restrict__ m1b3,
        const float* __restrict__ m2w1, const float* __restrict__ m2b1,
        const float* __restrict__ m2w2, const float* __restrict__ m2b2,
        const float* __restrict__ ow1, const float* __restrict__ ob1,
        const float* __restrict__ ow2, const float* __restrict__ ob2,
        float* __restrict__ hidden, float* __restrict__ msg_base,
        float* __restrict__ agg, const float* __restrict__ aggB,
        float* __restrict__ out, int t) {
    const int gid = blockIdx.x * 256 + threadIdx.x;
    const int n = gid >> 2;
    const int q = gid & 3;
    if (n >= NN) return;

    float a;
    if (SORTED) {
        const int b = n / BN;
        const int r = n - b * BN;
        const float* p = aggB + ((size_t)(b * NSLICE) + q * 8) * BN + r;
        float sA = 0.0f;
#pragma unroll
        for (int j = 0; j < 8; ++j) sA += p[(size_t)j * BN];
        sA += __shfl_xor(sA, 1);
        sA += __shfl_xor(sA, 2);
        a = sA;
    } else {
        a = agg[n];
    }

    const float x1 = SORTED ? x1T[t * NN + n] : x[(size_t)n * TT * 2 + t * 2 + 1];

    float2 hme = *reinterpret_cast<const float2*>(hidden + (size_t)n * 8 + q * 2);
    float hid[8];
    hid[0] = hme.x; hid[1] = hme.y;
    hid[2] = __shfl_xor(hid[0], 1); hid[3] = __shfl_xor(hid[1], 1);
    hid[4] = __shfl_xor(hid[0], 2); hid[5] = __shfl_xor(hid[1], 2);
    hid[6] = __shfl_xor(hid[2], 2); hid[7] = __shfl_xor(hid[3], 2);

    float acc[8];
    {
        float4 bA = ld4_(m2b1 + q * 8), bB = ld4_(m2b1 + q * 8 + 4);
        acc[0] = bA.x; acc[1] = bA.y; acc[2] = bA.z; acc[3] = bA.w;
        acc[4] = bB.x; acc[5] = bB.y; acc[6] = bB.z; acc[7] = bB.w;
    }
    fma_row8(acc, m2w1 + q * 8, x1);
#pragma unroll
    for (int g = 0; g < 4; ++g) {
        int rq = (q ^ g) * 2;
        fma_row8(acc, m2w1 + (size_t)(1 + rq) * 32 + q * 8, hid[g * 2 + 0]);
        fma_row8(acc, m2w1 + (size_t)(2 + rq) * 32 + q * 8, hid[g * 2 + 1]);
    }
    fma_row8(acc, m2w1 + (size_t)9 * 32 + q * 8, a);
    float u1[8];
#pragma unroll
    for (int jj = 0; jj < 8; ++jj) u1[jj] = reluf_(acc[jj]);

    float pk[8];
#pragma unroll
    for (int k = 0; k < 8; ++k) pk[k] = 0.0f;
#pragma unroll
    for (int jj = 0; jj < 8; ++jj)
        fma_row8(pk, m2w2 + (size_t)(q * 8 + jj) * 8, u1[jj]);
#pragma unroll
    for (int k = 0; k < 8; ++k) {
        pk[k] += __shfl_xor(pk[k], 1);
        pk[k] += __shfl_xor(pk[k], 2);
    }
    float hn[8];
    {
        float4 b2A = ld4_(m2b2), b2B = ld4_(m2b2 + 4);
        hn[0] = tanhf(reluf_(pk[0] + b2A.x));
        hn[1] = tanhf(reluf_(pk[1] + b2A.y));
        hn[2] = tanhf(reluf_(pk[2] + b2A.z));
        hn[3] = tanhf(reluf_(pk[3] + b2A.w));
        hn[4] = tanhf(reluf_(pk[4] + b2B.x));
        hn[5] = tanhf(reluf_(pk[5] + b2B.y));
        hn[6] = tanhf(reluf_(pk[6] + b2B.z));
        hn[7] = tanhf(reluf_(pk[7] + b2B.w));
    }
    if (q == 0) {
        *reinterpret_cast<float4*>(hidden + (size_t)n * 8)     = make_float4(hn[0], hn[1], hn[2], hn[3]);
        *reinterpret_cast<float4*>(hidden + (size_t)n * 8 + 4) = make_float4(hn[4], hn[5], hn[6], hn[7]);
    }

    float o1v[4];
    {
        float4 ob = ld4_(ob1 + q * 4);
        o1v[0] = ob.x; o1v[1] = ob.y; o1v[2] = ob.z; o1v[3] = ob.w;
    }
#pragma unroll
    for (int k = 0; k < 8; ++k) {
        float4 wv = ld4_(ow1 + k * 16 + q * 4);
        o1v[0] += hn[k] * wv.x; o1v[1] += hn[k] * wv.y;
        o1v[2] += hn[k] * wv.z; o1v[3] += hn[k] * wv.w;
    }
    {
        float4 w2v = ld4_(ow2 + q * 4);
        float oop = reluf_(o1v[0]) * w2v.x + reluf_(o1v[1]) * w2v.y +
                    reluf_(o1v[2]) * w2v.z + reluf_(o1v[3]) * w2v.w;
        oop += __shfl_xor(oop, 1);
        oop += __shfl_xor(oop, 2);
        if (q == 0) out[t * NN + n] = sigmoidf_(oop + ob2[0]);
    }

    if (t < TT - 1) {
        float feat0 = SORTED ? x0T[(t + 1) * NN + n] : x[(size_t)n * TT * 2 + (t + 1) * 2];
        float h1[8];
        {
            float4 bA = ld4_(m1b1 + q * 8), bB = ld4_(m1b1 + q * 8 + 4);
            h1[0] = bA.x; h1[1] = bA.y; h1[2] = bA.z; h1[3] = bA.w;
            h1[4] = bB.x; h1[5] = bB.y; h1[6] = bB.z; h1[7] = bB.w;
        }
        fma_row8(h1, m1w1 + q * 8, feat0);
#pragma unroll
        for (int k = 0; k < 8; ++k)
            fma_row8(h1, m1w1 + (size_t)(1 + k) * 32 + q * 8, hn[k]);
#pragma unroll
        for (int jj = 0; jj < 8; ++jj) h1[jj] = reluf_(h1[jj]);

        float h1x[32];
#pragma unroll
        for (int jj = 0; jj < 8; ++jj) h1x[jj] = h1[jj];
#pragma unroll
        for (int jj = 0; jj < 8; ++jj) h1x[8 + jj]  = __shfl_xor(h1x[jj], 1);
#pragma unroll
        for (int jj = 0; jj < 8; ++jj) h1x[16 + jj] = __shfl_xor(h1x[jj], 2);
#pragma unroll
        for (int jj = 0; jj < 8; ++jj) h1x[24 + jj] = __shfl_xor(h1x[8 + jj], 2);

        float acc8[8];
        {
            float4 bA = ld4_(m1b2 + q * 8), bB = ld4_(m1b2 + q * 8 + 4);
            acc8[0] = bA.x; acc8[1] = bA.y; acc8[2] = bA.z; acc8[3] = bA.w;
            acc8[4] = bB.x; acc8[5] = bB.y; acc8[6] = bB.z; acc8[7] = bB.w;
        }
#pragma unroll
        for (int g = 0; g < 4; ++g) {
            int rb = (q ^ g) * 8;
#pragma unroll
            for (int jj = 0; jj < 8; ++jj)
                fma_row8(acc8, m1w2 + (size_t)(rb + jj) * 32 + q * 8, h1x[g * 8 + jj]);
        }
        float s3;
        {
            float4 w3a = ld4_(m1w3 + q * 8), w3b = ld4_(m1w3 + q * 8 + 4);
            s3 = reluf_(acc8[0]) * w3a.x + reluf_(acc8[1]) * w3a.y +
                 reluf_(acc8[2]) * w3a.z + reluf_(acc8[3]) * w3a.w +
                 reluf_(acc8[4]) * w3b.x + reluf_(acc8[5]) * w3b.y +
                 reluf_(acc8[6]) * w3b.z + reluf_(acc8[7]) * w3b.w;
        }
        s3 += __shfl_xor(s3, 1);
        s3 += __shfl_xor(s3, 2);
        if (q == 0) {
            msg_base[n] = sigmoidf_(s3 + m1b3[0]);
            if (!SORTED) agg[n] = 0.0f;
        }
    }
}

extern "C" void kernel_launch(void* const* d_in, const int* in_sizes, int n_in,
                              void* d_out, int out_size, void* d_ws, size_t ws_size,
                              hipStream_t stream) {
    (void)in_sizes; (void)n_in; (void)out_size;
    const float* x    = (const float*)d_in[0];
    const int*   ei   = (const int*)d_in[1];
    const float* ea   = (const float*)d_in[2];
    const float* m1w1 = (const float*)d_in[3];
    const float* m1b1 = (const float*)d_in[4];
    const float* m1w2 = (const float*)d_in[5];
    const float* m1b2 = (const float*)d_in[6];
    const float* m1w3 = (const float*)d_in[7];
    const float* m1b3 = (const float*)d_in[8];
    const float* m2w1 = (const float*)d_in[9];
    const float* m2b1 = (const float*)d_in[10];
    const float* m2w2 = (const float*)d_in[11];
    const float* m2b2 = (const float*)d_in[12];
    const float* ow1  = (const float*)d_in[13];
    const float* ob1  = (const float*)d_in[14];
    const float* ow2  = (const float*)d_in[15];
    const float* ob2  = (const float*)d_in[16];
    float* out = (float*)d_out;

    // Workspace carve (all offsets stay 16B-aligned)
    char* wp = (char*)d_ws;
    float* hidden   = (float*)wp; wp += (size_t)NN * 8 * 4;       // 1.6 MB
    float* msg_base = (float*)wp; wp += (size_t)NN * 4;           // 200 KB
    float* agg      = (float*)wp; wp += (size_t)NN * 4;           // 200 KB (legacy)
    float* x0T      = (float*)wp; wp += (size_t)NN * TT * 4;      // 2 MB
    float* x1T      = (float*)wp; wp += (size_t)NN * TT * 4;      // 2 MB
    int4*  srt      = (int4*)wp;  wp += (size_t)TT * EE * 16;     // 160 MB
    unsigned* chist   = (unsigned*)wp; wp += (size_t)TT * NB * CHPAD * 4;  // 328 KB
    unsigned* total   = (unsigned*)wp; wp += (size_t)TT * NB * 4;
    unsigned* segBase = (unsigned*)wp; wp += (size_t)TT * NB * 4;
    float* aggB     = (float*)wp; wp += (size_t)NB * NSLICE * BN * 4;      // 6.4 MB
    size_t need = (size_t)(wp - (char*)d_ws);

    int sorted = (ws_size >= need) ? 1 : 0;

    dim3 blk(256);
    int nodeBlocks  = (NN + 255) / 256;
    int node4Blocks = (NN * 4 + 255) / 256;
    int edgeBlocksLegacy = (EE / 2 + 255) / 256;

    pre_kernel<<<nodeBlocks, blk, 0, stream>>>(x, m1w1, m1b1, m1w2, m1b2, m1w3, m1b3,
                                               hidden, msg_base, agg, x0T, x1T, sorted);
    if (sorted) {
        hist16_kernel<<<NCHUNK, blk, 0, stream>>>(ei, chist);
        scan_kernel<<<TT * NB, dim3(64), 0, stream>>>(chist, total);
        segbase_kernel<<<1, dim3(64), 0, stream>>>(total, segBase);
        reorder_kernel<<<NCHUNK, blk, 0, stream>>>(ei, ea, chist, segBase, srt);
    }
    for (int t = 0; t < TT; ++t) {
        if (sorted) {
            edge_srt_kernel<<<NB * NSLICE, blk, 0, stream>>>(srt, segBase, total,
                                                             msg_base, aggB, t);
            node4_kernel<1><<<node4Blocks, blk, 0, stream>>>(
                x, x0T, x1T,
                m1w1, m1b1, m1w2, m1b2, m1w3, m1b3,
                m2w1, m2b1, m2w2, m2b2,
                ow1, ob1, ow2, ob2,
                hidden, msg_base, agg, aggB, out, t);
        } else {
            edge_kernel<<<edgeBlocksLegacy, blk, 0, stream>>>(ei, ea, msg_base, agg, t);
            node4_kernel<0><<<node4Blocks, blk, 0, stream>>>(
                x, x0T, x1T,
                m1w1, m1b1, m1w2, m1b2, m1w3, m1b3,
                m2w1, m2b1, m2w2, m2b2,
                ow1, ob1, ow2, ob2,
                hidden, msg_base, agg, aggB, out, t);
        }
    }
}